// Round 2
// baseline (246.537 us; speedup 1.0000x reference)
//
#include <hip/hip_runtime.h>
#include <hip/hip_cooperative_groups.h>
#include <cmath>

namespace cg = cooperative_groups;

// Problem constants (from reference setup_inputs)
#define B_  32
#define S_  52
#define A_  5
#define C_  80
#define T_  50
#define PD_ (A_ * (5 + C_))   // 425 channels per spatial cell
#define NCELL (B_ * S_ * S_)  // 86528 = 338 * 256 exactly
#define NB_CONF (NCELL / 256) // 338 conf blocks, one cell per thread
#define NB_TGT  B_            // 32 target blocks
#define NBLOCKS (NB_TGT + NB_CONF)  // 370

// ws layout (floats), all plain stores (no init needed, no atomics):
//   ws[0 .. NB_CONF-1]                : per-block conf^2 partial sums
//   ws[NB_CONF + b*4 + {0,1,2,3}]     : per-image {s_off, s_scale, s_obj, s_conf2win}
#define WS_TGT NB_CONF

__constant__ float c_anchors[A_ * 2] = {
    1.3221f, 1.73145f,
    3.19275f, 4.00944f,
    5.05587f, 8.09892f,
    9.47112f, 4.84053f,
    11.2364f, 10.0071f
};

__device__ __forceinline__ float sigmoidf_(float x) {
    return 1.0f / (1.0f + __expf(-x));
}

// Single cooperative kernel.
//  blocks [0, NB_TGT)              : per-image target terms (long latency chain -> first)
//  blocks [NB_TGT, NBLOCKS)        : sum of sigmoid(obj)^2, one spatial cell per thread
//  grid.sync(), then block 0 composes the three outputs.
__global__ __launch_bounds__(256) void yolo_fused_kernel(
        const float* __restrict__ pred, const float* __restrict__ tgt,
        float* __restrict__ ws, float* __restrict__ out) {
    __shared__ float lds4[4];
    __shared__ int cellids[T_];
    __shared__ float red[4][5];

    if (blockIdx.x < NB_TGT) {
        // ---------------- target part: one image per block, lane t = target t ----
        const int b = blockIdx.x;
        const int t = threadIdx.x;

        float gx = 0.f, gy = 0.f, gw = 0.f, gh = 0.f;
        float baw = 1.f, bah = 1.f;
        int best_a = 0, gi = 0, gj = 0;
        const bool active = (t < T_);

        if (active) {
            const float* tp = tgt + ((size_t)b * T_ + t) * 5;
            gx = tp[0]; gy = tp[1]; gw = tp[2]; gh = tp[3];
            float gtw = gw * S_, gth = gh * S_;
            float best = -1.0f;
            #pragma unroll
            for (int a = 0; a < A_; ++a) {
                float aw = c_anchors[2 * a], ah = c_anchors[2 * a + 1];
                float inter = fminf(gtw, aw) * fminf(gth, ah);
                float uni = gtw * gth + aw * ah - inter;
                float iou = (uni > 0.0f) ? (inter / uni) : 0.0f;
                if (iou > best) { best = iou; best_a = a; baw = aw; bah = ah; } // first-max wins
            }
            gi = (int)(gx * S_);   // truncation == floor for positives
            gj = (int)(gy * S_);
            cellids[t] = (best_a * S_ + gj) * S_ + gi;
        }
        __syncthreads();

        // last-target-wins dedupe (matches sequential scatter semantics)
        bool winner = active;
        if (active) {
            int myid = cellids[t];
            for (int u = t + 1; u < T_; ++u)
                if (cellids[u] == myid) { winner = false; break; }
        }

        float s_off = 0.f, s_scale = 0.f, s_obj = 0.f, s_c2 = 0.f;
        if (winner) {
            float gtw = gw * S_, gth = gh * S_;
            const float* p = pred + (((size_t)b * S_ + gj) * S_ + gi) * PD_ + best_a * 85;
            float tx = p[0], ty = p[1], tw = p[2], th = p[3], to = p[4];

            float pbx = sigmoidf_(tx), pby = sigmoidf_(ty);
            float pbw = __expf(tw) * baw, pbh = __expf(th) * bah;
            float ggx = gx * S_ - (float)gi, ggy = gy * S_ - (float)gj;

            float cx1 = ggx + (float)gi, cy1 = ggy + (float)gj;
            float cx2 = pbx + (float)gi, cy2 = pby + (float)gj;
            float ix = fmaxf(0.0f, fminf(cx1 + gtw * 0.5f, cx2 + pbw * 0.5f)
                                 - fmaxf(cx1 - gtw * 0.5f, cx2 - pbw * 0.5f));
            float iy = fmaxf(0.0f, fminf(cy1 + gth * 0.5f, cy2 + pbh * 0.5f)
                                 - fmaxf(cy1 - gth * 0.5f, cy2 - pbh * 0.5f));
            float inter = ix * iy;
            float uni = gtw * gth + pbw * pbh - inter;
            float iou = (uni > 0.0f) ? (inter / uni) : 0.0f;

            float conf = sigmoidf_(to);

            s_off = (pbx - ggx) * (pbx - ggx) + (pby - ggy) * (pby - ggy);
            const float eps = 1e-6f;
            float dw = sqrtf(pbw + eps) - sqrtf(gtw + eps);
            float dh = sqrtf(pbh + eps) - sqrtf(gth + eps);
            s_scale = dw * dw + dh * dh;
            s_obj = (iou - conf) * (iou - conf);
            s_c2 = conf * conf;  // remove this winner cell from the no-obj sum
        }

        if (t < 64) {   // all targets live in wave 0; lanes >= T_ carry zeros
            #pragma unroll
            for (int off = 32; off > 0; off >>= 1) {
                s_off   += __shfl_down(s_off,   off, 64);
                s_scale += __shfl_down(s_scale, off, 64);
                s_obj   += __shfl_down(s_obj,   off, 64);
                s_c2    += __shfl_down(s_c2,    off, 64);
            }
            if (t == 0) {
                float* w = ws + WS_TGT + b * 4;
                w[0] = s_off; w[1] = s_scale; w[2] = s_obj; w[3] = s_c2;
            }
        }
    } else {
        // ---------------- conf^2 part: one cell per thread, 5 independent loads ----
        const int cell = (blockIdx.x - NB_TGT) * 256 + threadIdx.x;  // < 86528 exact
        const float* p = pred + (size_t)cell * PD_;
        // obj channels at a*85+4
        float c0 = p[4];
        float c1 = p[89];
        float c2 = p[174];
        float c3 = p[259];
        float c4 = p[344];
        c0 = sigmoidf_(c0); c1 = sigmoidf_(c1); c2 = sigmoidf_(c2);
        c3 = sigmoidf_(c3); c4 = sigmoidf_(c4);
        float v = c0 * c0 + c1 * c1 + c2 * c2 + c3 * c3 + c4 * c4;

        #pragma unroll
        for (int off = 32; off > 0; off >>= 1)
            v += __shfl_down(v, off, 64);
        int lane = threadIdx.x & 63;
        int wv = threadIdx.x >> 6;
        if (lane == 0) lds4[wv] = v;
        __syncthreads();
        if (threadIdx.x == 0)
            ws[blockIdx.x - NB_TGT] = lds4[0] + lds4[1] + lds4[2] + lds4[3];
    }

    // ---------------- grid-wide barrier, then block 0 composes outputs --------
    cg::this_grid().sync();

    if (blockIdx.x == 0) {
        const int t = threadIdx.x;

        float sc = 0.f;
        for (int i = t; i < NB_CONF; i += 256)
            sc += ws[i];

        float s_off = 0.f, s_scale = 0.f, s_obj = 0.f, s_c2 = 0.f;
        if (t < NB_TGT) {
            const float* w = ws + WS_TGT + t * 4;
            s_off = w[0]; s_scale = w[1]; s_obj = w[2]; s_c2 = w[3];
        }

        #pragma unroll
        for (int off = 32; off > 0; off >>= 1) {
            sc      += __shfl_down(sc,      off, 64);
            s_off   += __shfl_down(s_off,   off, 64);
            s_scale += __shfl_down(s_scale, off, 64);
            s_obj   += __shfl_down(s_obj,   off, 64);
            s_c2    += __shfl_down(s_c2,    off, 64);
        }

        int lane = t & 63, wv = t >> 6;
        if (lane == 0) {
            red[wv][0] = sc; red[wv][1] = s_off; red[wv][2] = s_scale;
            red[wv][3] = s_obj; red[wv][4] = s_c2;
        }
        __syncthreads();
        if (t == 0) {
            float S_all = 0.f, F = 0.f, SCL = 0.f, OB = 0.f, C2 = 0.f;
            #pragma unroll
            for (int w = 0; w < 4; ++w) {
                S_all += red[w][0]; F += red[w][1]; SCL += red[w][2];
                OB += red[w][3]; C2 += red[w][4];
            }
            float loss_coord  = 5.0f * (F + SCL);
            float loss_no_obj = 0.5f * (S_all - C2);
            float loss_obj    = OB;
            out[0] = 5.0f * loss_coord + loss_obj + 0.5f * loss_no_obj;
            out[1] = loss_coord;
            out[2] = loss_obj + loss_no_obj;
        }
    }
}

extern "C" void kernel_launch(void* const* d_in, const int* in_sizes, int n_in,
                              void* d_out, int out_size, void* d_ws, size_t ws_size,
                              hipStream_t stream) {
    const float* pred = (const float*)d_in[0];   // [32,52,52,425]
    const float* tgt  = (const float*)d_in[1];   // [32,50,5]
    float* out = (float*)d_out;                  // 3 scalars
    float* ws  = (float*)d_ws;                   // 338 + 128 floats of partials

    void* args[] = { (void*)&pred, (void*)&tgt, (void*)&ws, (void*)&out };
    hipLaunchCooperativeKernel((void*)yolo_fused_kernel,
                               dim3(NBLOCKS), dim3(256), args, 0, stream);
}

// Round 3
// 189.298 us; speedup vs baseline: 1.3024x; 1.3024x over previous
//
#include <hip/hip_runtime.h>
#include <cmath>

// Problem constants (from reference setup_inputs)
#define B_  32
#define S_  52
#define A_  5
#define C_  80
#define T_  50
#define PD_ (A_ * (5 + C_))   // 425 channels per spatial cell
#define NCELL (B_ * S_ * S_)  // 86528 = 169 * 512 exactly
#define CPB   512             // cells per conf block (2 per thread)
#define NB_CONF (NCELL / CPB) // 169 conf blocks
#define NB_TGT  B_            // 32 target blocks; total 201 blocks <= 256 CUs

// ws layout (floats), all plain stores (no init needed, no atomics):
//   ws[0 .. NB_CONF-1]                : per-block conf^2 partial sums
//   ws[NB_CONF + b*4 + {0,1,2,3}]     : per-image {s_off, s_scale, s_obj, s_conf2win}
#define WS_TGT NB_CONF

__constant__ float c_anchors[A_ * 2] = {
    1.3221f, 1.73145f,
    3.19275f, 4.00944f,
    5.05587f, 8.09892f,
    9.47112f, 4.84053f,
    11.2364f, 10.0071f
};

__device__ __forceinline__ float sigmoidf_(float x) {
    return 1.0f / (1.0f + __expf(-x));
}

// Fused kernel.
//  blocks [0, NB_TGT)              : per-image target terms (long latency chain -> first)
//  blocks [NB_TGT, NB_TGT+NB_CONF) : sum of sigmoid(obj)^2, two cells per thread
__global__ __launch_bounds__(256) void fused_kernel(
        const float* __restrict__ pred, const float* __restrict__ tgt,
        float* __restrict__ ws) {
    __shared__ float lds4[4];
    __shared__ int cellids[T_];

    if (blockIdx.x < NB_TGT) {
        // ---------------- target part: one image per block, lane t = target t ----
        const int b = blockIdx.x;
        const int t = threadIdx.x;

        float gx = 0.f, gy = 0.f, gw = 0.f, gh = 0.f;
        float baw = 1.f, bah = 1.f;
        int best_a = 0, gi = 0, gj = 0;
        const bool active = (t < T_);

        if (active) {
            const float* tp = tgt + ((size_t)b * T_ + t) * 5;
            gx = tp[0]; gy = tp[1]; gw = tp[2]; gh = tp[3];
            float gtw = gw * S_, gth = gh * S_;
            float best = -1.0f;
            #pragma unroll
            for (int a = 0; a < A_; ++a) {
                float aw = c_anchors[2 * a], ah = c_anchors[2 * a + 1];
                float inter = fminf(gtw, aw) * fminf(gth, ah);
                float uni = gtw * gth + aw * ah - inter;
                float iou = (uni > 0.0f) ? (inter / uni) : 0.0f;
                if (iou > best) { best = iou; best_a = a; baw = aw; bah = ah; } // first-max wins
            }
            gi = (int)(gx * S_);   // truncation == floor for positives
            gj = (int)(gy * S_);
            cellids[t] = (best_a * S_ + gj) * S_ + gi;
        }
        __syncthreads();

        // last-target-wins dedupe (matches sequential scatter semantics)
        bool winner = active;
        if (active) {
            int myid = cellids[t];
            for (int u = t + 1; u < T_; ++u)
                if (cellids[u] == myid) { winner = false; break; }
        }

        float s_off = 0.f, s_scale = 0.f, s_obj = 0.f, s_c2 = 0.f;
        if (winner) {
            float gtw = gw * S_, gth = gh * S_;
            const float* p = pred + (((size_t)b * S_ + gj) * S_ + gi) * PD_ + best_a * 85;
            float tx = p[0], ty = p[1], tw = p[2], th = p[3], to = p[4];

            float pbx = sigmoidf_(tx), pby = sigmoidf_(ty);
            float pbw = __expf(tw) * baw, pbh = __expf(th) * bah;
            float ggx = gx * S_ - (float)gi, ggy = gy * S_ - (float)gj;

            float cx1 = ggx + (float)gi, cy1 = ggy + (float)gj;
            float cx2 = pbx + (float)gi, cy2 = pby + (float)gj;
            float ix = fmaxf(0.0f, fminf(cx1 + gtw * 0.5f, cx2 + pbw * 0.5f)
                                 - fmaxf(cx1 - gtw * 0.5f, cx2 - pbw * 0.5f));
            float iy = fmaxf(0.0f, fminf(cy1 + gth * 0.5f, cy2 + pbh * 0.5f)
                                 - fmaxf(cy1 - gth * 0.5f, cy2 - pbh * 0.5f));
            float inter = ix * iy;
            float uni = gtw * gth + pbw * pbh - inter;
            float iou = (uni > 0.0f) ? (inter / uni) : 0.0f;

            float conf = sigmoidf_(to);

            s_off = (pbx - ggx) * (pbx - ggx) + (pby - ggy) * (pby - ggy);
            const float eps = 1e-6f;
            float dw = sqrtf(pbw + eps) - sqrtf(gtw + eps);
            float dh = sqrtf(pbh + eps) - sqrtf(gth + eps);
            s_scale = dw * dw + dh * dh;
            s_obj = (iou - conf) * (iou - conf);
            s_c2 = conf * conf;  // remove this winner cell from the no-obj sum
        }

        if (t < 64) {   // all targets live in wave 0; lanes >= T_ carry zeros
            #pragma unroll
            for (int off = 32; off > 0; off >>= 1) {
                s_off   += __shfl_down(s_off,   off, 64);
                s_scale += __shfl_down(s_scale, off, 64);
                s_obj   += __shfl_down(s_obj,   off, 64);
                s_c2    += __shfl_down(s_c2,    off, 64);
            }
            if (t == 0) {
                float* w = ws + WS_TGT + b * 4;
                w[0] = s_off; w[1] = s_scale; w[2] = s_obj; w[3] = s_c2;
            }
        }
    } else {
        // ------------- conf^2 part: two cells per thread, 10 independent loads ----
        const int cell0 = (blockIdx.x - NB_TGT) * CPB + threadIdx.x;  // + {0, 256}
        const float* p0 = pred + (size_t)cell0 * PD_;
        const float* p1 = p0 + (size_t)256 * PD_;
        // obj channels at a*85+4; issue all 10 loads before any math
        float c0 = p0[4],  c1 = p0[89],  c2 = p0[174], c3 = p0[259], c4 = p0[344];
        float d0 = p1[4],  d1 = p1[89],  d2 = p1[174], d3 = p1[259], d4 = p1[344];
        c0 = sigmoidf_(c0); c1 = sigmoidf_(c1); c2 = sigmoidf_(c2);
        c3 = sigmoidf_(c3); c4 = sigmoidf_(c4);
        d0 = sigmoidf_(d0); d1 = sigmoidf_(d1); d2 = sigmoidf_(d2);
        d3 = sigmoidf_(d3); d4 = sigmoidf_(d4);
        float v = c0 * c0 + c1 * c1 + c2 * c2 + c3 * c3 + c4 * c4
                + d0 * d0 + d1 * d1 + d2 * d2 + d3 * d3 + d4 * d4;

        #pragma unroll
        for (int off = 32; off > 0; off >>= 1)
            v += __shfl_down(v, off, 64);
        int lane = threadIdx.x & 63;
        int wv = threadIdx.x >> 6;
        if (lane == 0) lds4[wv] = v;
        __syncthreads();
        if (threadIdx.x == 0)
            ws[blockIdx.x - NB_TGT] = lds4[0] + lds4[1] + lds4[2] + lds4[3];
    }
}

// Reduce partials and compose the three outputs (lambdas applied twice, per reference).
__global__ __launch_bounds__(256) void reduce_kernel(
        const float* __restrict__ ws, float* __restrict__ out) {
    const int t = threadIdx.x;

    float sc = 0.f;
    if (t < NB_CONF) sc = ws[t];   // 169 partials, one per lane

    float s_off = 0.f, s_scale = 0.f, s_obj = 0.f, s_c2 = 0.f;
    if (t < NB_TGT) {
        const float* w = ws + WS_TGT + t * 4;
        s_off = w[0]; s_scale = w[1]; s_obj = w[2]; s_c2 = w[3];
    }

    #pragma unroll
    for (int off = 32; off > 0; off >>= 1) {
        sc      += __shfl_down(sc,      off, 64);
        s_off   += __shfl_down(s_off,   off, 64);
        s_scale += __shfl_down(s_scale, off, 64);
        s_obj   += __shfl_down(s_obj,   off, 64);
        s_c2    += __shfl_down(s_c2,    off, 64);
    }

    __shared__ float red[4][5];
    int lane = t & 63, wv = t >> 6;
    if (lane == 0) {
        red[wv][0] = sc; red[wv][1] = s_off; red[wv][2] = s_scale;
        red[wv][3] = s_obj; red[wv][4] = s_c2;
    }
    __syncthreads();
    if (t == 0) {
        float S_all = 0.f, F = 0.f, SCL = 0.f, OB = 0.f, C2 = 0.f;
        #pragma unroll
        for (int w = 0; w < 4; ++w) {
            S_all += red[w][0]; F += red[w][1]; SCL += red[w][2];
            OB += red[w][3]; C2 += red[w][4];
        }
        float loss_coord  = 5.0f * (F + SCL);
        float loss_no_obj = 0.5f * (S_all - C2);
        float loss_obj    = OB;
        out[0] = 5.0f * loss_coord + loss_obj + 0.5f * loss_no_obj;
        out[1] = loss_coord;
        out[2] = loss_obj + loss_no_obj;
    }
}

extern "C" void kernel_launch(void* const* d_in, const int* in_sizes, int n_in,
                              void* d_out, int out_size, void* d_ws, size_t ws_size,
                              hipStream_t stream) {
    const float* pred = (const float*)d_in[0];   // [32,52,52,425]
    const float* tgt  = (const float*)d_in[1];   // [32,50,5]
    float* out = (float*)d_out;                  // 3 scalars
    float* ws  = (float*)d_ws;                   // 169 + 128 floats of partials

    // No memset: all workspace slots are written by plain stores each iteration.
    fused_kernel<<<NB_TGT + NB_CONF, 256, 0, stream>>>(pred, tgt, ws);
    reduce_kernel<<<1, 256, 0, stream>>>(ws, out);
}